// Round 1
// baseline (138.273 us; speedup 1.0000x reference)
//
#include <hip/hip_runtime.h>

// HashEncoding: 65536 pts x 16 levels, F=16, dense levels 0..5, hash levels 6..15.
// out[p*19 + 0..2] = xn, out[p*19 + 3 + l] = sum_f of bilinear(x,y)-weighted 8-corner gather.

#define HE_T_PRIME 1048583ULL

static __device__ __constant__ int c_num[16] = {
    16, 22, 30, 42, 58, 80, 110, 152, 210, 290, 400, 553, 763, 1053, 1453, 2005};
// float32(1.0/(num-1)) computed in double then rounded — matches numpy's
// (1.0/(ENTRIES_NUM-1)).astype(np.float32) bit-exactly.
static __device__ __constant__ float c_es[16] = {
    (float)(1.0 / 15.0),   (float)(1.0 / 21.0),   (float)(1.0 / 29.0),
    (float)(1.0 / 41.0),   (float)(1.0 / 57.0),   (float)(1.0 / 79.0),
    (float)(1.0 / 109.0),  (float)(1.0 / 151.0),  (float)(1.0 / 209.0),
    (float)(1.0 / 289.0),  (float)(1.0 / 399.0),  (float)(1.0 / 552.0),
    (float)(1.0 / 762.0),  (float)(1.0 / 1052.0), (float)(1.0 / 1452.0),
    (float)(1.0 / 2004.0)};
// cumulative dense offsets: [0] + cumsum(num^3)[:5]
static __device__ __constant__ int c_doff[6] = {0, 4096, 14744, 41744, 115832, 310944};

__global__ __launch_bounds__(256) void HashEncoding_721554506107_kernel(
    const float* __restrict__ xyz, const float* __restrict__ dense,
    const float* __restrict__ hasht, float* __restrict__ out, int npts) {
  int tid = blockIdx.x * blockDim.x + threadIdx.x;
  int p = tid >> 4;
  if (p >= npts) return;
  int l = tid & 15;

  float px = xyz[3 * p + 0];
  float py = xyz[3 * p + 1];
  float pz = xyz[3 * p + 2];
  // xn = (x - lo) / (hi - lo) = (x + 2) / 4  (exact power-of-2 divide)
  float xn0 = (px + 2.0f) * 0.25f;
  float xn1 = (py + 2.0f) * 0.25f;
  float xn2 = (pz + 2.0f) * 0.25f;
  if (l < 3) out[19 * p + l] = (l == 0) ? xn0 : ((l == 1) ? xn1 : xn2);

  int n = c_num[l];
  float es = c_es[l];
  // IEEE f32 division — must match numpy's xn/es rounding (no fast-math).
  float fx = xn0 / es;
  float fy = xn1 / es;
  float fz = xn2 / es;
  int nm1 = n - 1;
  // corner-0 index: trunc(flt), clipped
  int ix0 = min(max((int)fx, 0), nm1);
  int iy0 = min(max((int)fy, 0), nm1);
  int iz0 = min(max((int)fz, 0), nm1);
  // corner-1 index: trunc(flt + 1.0f) — the f32 ADD can round across an
  // integer boundary, so do the add exactly as the reference does.
  int ix1 = min(max((int)(fx + 1.0f), 0), nm1);
  int iy1 = min(max((int)(fy + 1.0f), 0), nm1);
  int iz1 = min(max((int)(fz + 1.0f), 0), nm1);

  float ox = fx - (float)ix0;
  float oy = fy - (float)iy0;
  float wx[2] = {1.0f - ox, ox};
  float wy[2] = {1.0f - oy, oy};

  // 8 corner entry indices; OFFSETS order: c = x*4 + y*2 + z
  size_t idx[8];
  const float* tab;
  if (l < 6) {
    tab = dense;
    long long nn = (long long)n * (long long)n;
    long long doff = (long long)c_doff[l];
    long long ix[2] = {ix0, ix1};
    long long iy[2] = {iy0, iy1};
    long long iz[2] = {iz0, iz1};
#pragma unroll
    for (int c = 0; c < 8; ++c) {
      long long ind = ix[(c >> 2) & 1] * nn + iy[(c >> 1) & 1] * (long long)n +
                      iz[c & 1] + doff;
      idx[c] = (size_t)ind;
    }
  } else {
    tab = hasht + (size_t)(l - 6) * (size_t)(HE_T_PRIME * 16ULL);
    unsigned long long hx[2] = {(unsigned long long)ix0,
                                (unsigned long long)ix1};
    unsigned long long hy[2] = {(unsigned long long)iy0 * 19349663ULL,
                                (unsigned long long)iy1 * 19349663ULL};
    unsigned long long hz[2] = {(unsigned long long)iz0 * 83492791ULL,
                                (unsigned long long)iz1 * 83492791ULL};
#pragma unroll
    for (int c = 0; c < 8; ++c) {
      unsigned long long h = hx[(c >> 2) & 1] ^ hy[(c >> 1) & 1] ^ hz[c & 1];
      idx[c] = (size_t)(h % HE_T_PRIME);
    }
  }

  float acc = 0.0f;
#pragma unroll
  for (int c = 0; c < 8; ++c) {
    const float4* e = (const float4*)(tab + idx[c] * 16);
    float4 a = e[0];
    float4 b = e[1];
    float4 d = e[2];
    float4 g = e[3];
    float s = ((a.x + a.y) + (a.z + a.w)) + ((b.x + b.y) + (b.z + b.w)) +
              ((d.x + d.y) + (d.z + d.w)) + ((g.x + g.y) + (g.z + g.w));
    float w = wx[(c >> 2) & 1] * wy[(c >> 1) & 1];
    acc = fmaf(w, s, acc);
  }
  out[19 * p + 3 + l] = acc;
}

extern "C" void kernel_launch(void* const* d_in, const int* in_sizes, int n_in,
                              void* d_out, int out_size, void* d_ws,
                              size_t ws_size, hipStream_t stream) {
  const float* xyz = (const float*)d_in[0];
  const float* dense = (const float*)d_in[1];
  const float* hasht = (const float*)d_in[2];
  float* out = (float*)d_out;
  int npts = in_sizes[0] / 3;
  int total = npts * 16;
  int block = 256;
  int grid = (total + block - 1) / block;
  HashEncoding_721554506107_kernel<<<grid, block, 0, stream>>>(xyz, dense, hasht,
                                                               out, npts);
}

// Round 2
// 117.701 us; speedup vs baseline: 1.1748x; 1.1748x over previous
//
#include <hip/hip_runtime.h>

// HashEncoding: 65536 pts x 16 levels, F=16, dense levels 0..5, hash levels 6..15.
// Layout: 4 lanes per (point, level). Lane q loads the q-th float4 of each
// 64-B corner entry, so one load instruction covers 16 entries / 16 cache
// lines (instead of 64) -> 4x fewer L1 tag lookups on the random-gather path.
// gridDim.y = level so co-resident blocks share one 67-MB hash table (L3-fit).

#define HE_T_PRIME 1048583ULL
typedef unsigned long long ull;

static __device__ __constant__ int c_num[16] = {
    16, 22, 30, 42, 58, 80, 110, 152, 210, 290, 400, 553, 763, 1053, 1453, 2005};
// float32(1.0/(num-1)) — matches numpy (1.0/(ENTRIES_NUM-1)).astype(np.float32).
static __device__ __constant__ float c_es[16] = {
    (float)(1.0 / 15.0),   (float)(1.0 / 21.0),   (float)(1.0 / 29.0),
    (float)(1.0 / 41.0),   (float)(1.0 / 57.0),   (float)(1.0 / 79.0),
    (float)(1.0 / 109.0),  (float)(1.0 / 151.0),  (float)(1.0 / 209.0),
    (float)(1.0 / 289.0),  (float)(1.0 / 399.0),  (float)(1.0 / 552.0),
    (float)(1.0 / 762.0),  (float)(1.0 / 1052.0), (float)(1.0 / 1452.0),
    (float)(1.0 / 2004.0)};
// cumulative dense offsets (entries): [0] + cumsum(num^3)[:5]
static __device__ __constant__ int c_doff[6] = {0, 4096, 14744, 41744, 115832, 310944};

__global__ __launch_bounds__(256) void HashEncoding_721554506107_kernel(
    const float* __restrict__ xyz, const float* __restrict__ dense,
    const float* __restrict__ hasht, float* __restrict__ out, int npts) {
  const int l = blockIdx.y;                         // level, uniform per block
  const int p = blockIdx.x * 64 + (threadIdx.x >> 2);
  const int q = threadIdx.x & 3;                    // quarter of the 64-B entry
  if (p >= npts) return;

  const float px = xyz[3 * p + 0];
  const float py = xyz[3 * p + 1];
  const float pz = xyz[3 * p + 2];
  // xn = (x + 2) / 4  (exact power-of-2 divide)
  const float xn0 = (px + 2.0f) * 0.25f;
  const float xn1 = (py + 2.0f) * 0.25f;
  const float xn2 = (pz + 2.0f) * 0.25f;
  if (l == 0 && q < 3) out[19 * p + q] = (q == 0) ? xn0 : ((q == 1) ? xn1 : xn2);

  const int n = c_num[l];
  const float es = c_es[l];
  // IEEE f32 division — must match numpy's xn/es rounding (no fast-math).
  const float fx = xn0 / es;
  const float fy = xn1 / es;
  const float fz = xn2 / es;
  const int nm1 = n - 1;
  // corner-0: trunc(flt) clipped; corner-1: trunc(flt + 1.0f) clipped —
  // the f32 add can round across an integer, reference truncates the SUM.
  const int ix0 = min(max((int)fx, 0), nm1);
  const int iy0 = min(max((int)fy, 0), nm1);
  const int iz0 = min(max((int)fz, 0), nm1);
  const int ix1 = min(max((int)(fx + 1.0f), 0), nm1);
  const int iy1 = min(max((int)(fy + 1.0f), 0), nm1);
  const int iz1 = min(max((int)(fz + 1.0f), 0), nm1);

  const float ox = fx - (float)ix0;
  const float oy = fy - (float)iy0;
  // corner c bits: (x=c>>2, y=(c>>1)&1, z=c&1); weight ignores z: w = wxy[c>>1]
  float wxy[4];
  wxy[0] = (1.0f - ox) * (1.0f - oy);
  wxy[1] = (1.0f - ox) * oy;
  wxy[2] = ox * (1.0f - oy);
  wxy[3] = ox * oy;

  float acc = 0.0f;
  if (l < 6) {
    const int nn = n * n;
    const int base = c_doff[l];
    const int ixs[2] = {ix0 * nn, ix1 * nn};
    const int iys[2] = {iy0 * n, iy1 * n};
    const int izs[2] = {iz0, iz1};
#pragma unroll
    for (int c = 0; c < 8; ++c) {
      const int ind = base + ixs[c >> 2] + iys[(c >> 1) & 1] + izs[c & 1];
      const float4 v =
          *(const float4*)(dense + (size_t)ind * 16 + (size_t)(q * 4));
      acc = fmaf(wxy[c >> 1], (v.x + v.y) + (v.z + v.w), acc);
    }
  } else {
    const float* tab = hasht + (size_t)(l - 6) * (size_t)(HE_T_PRIME * 16ULL);
    const ull hx[2] = {(ull)ix0, (ull)ix1};
    const ull hy[2] = {(ull)iy0 * 19349663ULL, (ull)iy1 * 19349663ULL};
    const ull hz[2] = {(ull)iz0 * 83492791ULL, (ull)iz1 * 83492791ULL};
#pragma unroll
    for (int c = 0; c < 8; ++c) {
      const ull h = hx[c >> 2] ^ hy[(c >> 1) & 1] ^ hz[c & 1];
      const size_t ind = (size_t)(h % HE_T_PRIME);
      const float4 v = *(const float4*)(tab + ind * 16 + (size_t)(q * 4));
      acc = fmaf(wxy[c >> 1], (v.x + v.y) + (v.z + v.w), acc);
    }
  }

  // reduce the 4 quarter-sums of this (point, level) quad
  acc += __shfl_xor(acc, 1);
  acc += __shfl_xor(acc, 2);
  if (q == 0) out[19 * p + 3 + l] = acc;
}

extern "C" void kernel_launch(void* const* d_in, const int* in_sizes, int n_in,
                              void* d_out, int out_size, void* d_ws,
                              size_t ws_size, hipStream_t stream) {
  const float* xyz = (const float*)d_in[0];
  const float* dense = (const float*)d_in[1];
  const float* hasht = (const float*)d_in[2];
  float* out = (float*)d_out;
  const int npts = in_sizes[0] / 3;
  dim3 grid((npts + 63) / 64, 16);
  HashEncoding_721554506107_kernel<<<grid, 256, 0, stream>>>(xyz, dense, hasht,
                                                             out, npts);
}